// Round 1
// baseline (198.897 us; speedup 1.0000x reference)
//
#include <hip/hip_runtime.h>

#define H 768
#define NH 12
#define HD 64
#define BB 4
#define SS 1024
#define MM (BB*SS)   // 4096 tokens

typedef __bf16 bf16;
typedef __bf16 bf16x8 __attribute__((ext_vector_type(8)));
typedef __bf16 bf16x4 __attribute__((ext_vector_type(4)));
typedef float  f32x4  __attribute__((ext_vector_type(4)));

static __device__ __forceinline__ f32x4 mfma16(bf16x8 a, bf16x8 b, f32x4 c){
  return __builtin_amdgcn_mfma_f32_16x16x32_bf16(a, b, c, 0, 0, 0);
}

// ---------------- prep: hs -> bf16 ----------------
__global__ __launch_bounds__(256) void prep_hs(const float* __restrict__ hs, bf16* __restrict__ hsb){
  size_t i = (size_t)blockIdx.x*256 + threadIdx.x;   // one float4 each
  f32x4 v = *(const f32x4*)(hs + i*4);
  bf16x4 o;
  #pragma unroll
  for(int j=0;j<4;j++) o[j] = (bf16)v[j];
  *(bf16x4*)(hsb + i*4) = o;
}

// ---------------- prep: W[k][n] -> bf16 W^T[n][k] (LDS tiled transpose) ----------------
__global__ __launch_bounds__(256) void prep_wt(const float* __restrict__ Wq, const float* __restrict__ Wk,
                                               const float* __restrict__ Wv, const float* __restrict__ Wo,
                                               bf16* __restrict__ oq, bf16* __restrict__ ok,
                                               bf16* __restrict__ ov, bf16* __restrict__ oo){
  int z = blockIdx.z;
  const float* W = (z==0)?Wq:(z==1)?Wk:(z==2)?Wv:Wo;
  bf16* O = (z==0)?oq:(z==1)?ok:(z==2)?ov:oo;
  __shared__ float tile[64][65];
  int t = threadIdx.x;
  int k0 = blockIdx.y*64, n0 = blockIdx.x*64;
  #pragma unroll
  for(int i=0;i<4;i++){
    int idx = i*256+t; int r = idx>>4; int c4 = (idx&15)*4;
    f32x4 v = *(const f32x4*)(W + (size_t)(k0+r)*H + n0 + c4);
    tile[r][c4+0]=v[0]; tile[r][c4+1]=v[1]; tile[r][c4+2]=v[2]; tile[r][c4+3]=v[3];
  }
  __syncthreads();
  #pragma unroll
  for(int i=0;i<4;i++){
    int idx = i*256+t; int r = idx>>4; int c4 = (idx&15)*4;
    bf16x4 o;
    #pragma unroll
    for(int j=0;j<4;j++) o[j] = (bf16)tile[c4+j][r];
    *(bf16x4*)(O + (size_t)(n0+r)*H + k0 + c4) = o;
  }
}

// ---------------- QKV GEMM: [4096,768] x W^T -> q/k/v bf16 [B,NH,S,HD] ----------------
__global__ __launch_bounds__(256) void qkv_gemm(const bf16* __restrict__ hsb,
    const bf16* __restrict__ wqT, const bf16* __restrict__ wkT, const bf16* __restrict__ wvT,
    const float* __restrict__ bq, const float* __restrict__ bk, const float* __restrict__ bv,
    bf16* __restrict__ qb, bf16* __restrict__ kb, bf16* __restrict__ vb){
  int t = threadIdx.x;
  int m0 = blockIdx.x*64;
  int by = blockIdx.y;                 // 0..35
  int mat = by/12, nb = by%12, n0 = nb*64;
  const bf16* wT   = (mat==0)?wqT:(mat==1)?wkT:wvT;
  const float* bias= (mat==0)?bq :(mat==1)?bk :bv;
  bf16* outp       = (mat==0)?qb :(mat==1)?kb :vb;
  float scale      = (mat==0)?0.125f:1.0f;   // 1/sqrt(64) on q

  __shared__ __align__(16) bf16 As[64*40];   // 64 rows x 32 k, +8 pad
  __shared__ __align__(16) bf16 Bs[64*40];
  int lane=t&63, w=t>>6, g=lane>>4, c=lane&15;
  f32x4 acc[4] = {};
  int ar = t>>2, asg = (t&3)*8;
  for(int kt=0; kt<24; kt++){
    __syncthreads();
    *(bf16x8*)&As[ar*40+asg] = *(const bf16x8*)(hsb + (size_t)(m0+ar)*H + kt*32 + asg);
    *(bf16x8*)&Bs[ar*40+asg] = *(const bf16x8*)(wT  + (size_t)(n0+ar)*H + kt*32 + asg);
    __syncthreads();
    bf16x8 a = *(const bf16x8*)&As[(16*w+c)*40 + g*8];
    #pragma unroll
    for(int ct=0;ct<4;ct++){
      bf16x8 b = *(const bf16x8*)&Bs[(16*ct+c)*40 + g*8];
      acc[ct] = mfma16(a, b, acc[ct]);
    }
  }
  #pragma unroll
  for(int ct=0;ct<4;ct++){
    #pragma unroll
    for(int r=0;r<4;r++){
      int row = m0 + 16*w + 4*g + r;       // token index
      int col = 16*ct + c;                 // d within head (n0 spans exactly one head)
      float val = (acc[ct][r] + bias[n0+col]) * scale;
      int b_ = row>>10, s = row&1023;
      outp[(((size_t)(b_*NH + nb))*SS + s)*HD + col] = (bf16)val;
    }
  }
}

// ---------------- attention: one block per (b, h, 64 q-rows) ----------------
__global__ __launch_bounds__(256) void attn_kernel(const bf16* __restrict__ qbuf,
    const bf16* __restrict__ kbuf, const bf16* __restrict__ vbuf,
    const float* __restrict__ relp, const float* __restrict__ rel2,
    bf16* __restrict__ ctxb){
  int t = threadIdx.x;
  int qt = blockIdx.x, h = blockIdx.y, b_ = blockIdx.z;
  int q0 = qt*64;
  const bf16* qh = qbuf + ((size_t)(b_*NH+h))*SS*HD;
  const bf16* kh = kbuf + ((size_t)(b_*NH+h))*SS*HD;
  const bf16* vh = vbuf + ((size_t)(b_*NH+h))*SS*HD;
  const float* r1 = relp + ((size_t)(b_*NH+h))*SS*SS;
  const float* r2 = rel2 + ((size_t)(b_*NH+h))*SS*SS;

  __shared__ __align__(16) float relS[64][68];   // rel1+rel2 tile, padded
  __shared__ __align__(16) bf16 Ks[64*64];       // [s][d], XOR-swizzled: idx = s*64 + (d ^ ((s&7)<<3))
  __shared__ __align__(16) bf16 Vs[64*64];       // [d][s], XOR-swizzled: idx = d*64 + (s ^ ((d&7)<<3))
  __shared__ __align__(16) bf16 Ps[4][1024];     // per-wave P transpose, idx = row*64 + (col ^ ((row&7)<<3))

  int lane=t&63, w=t>>6, g=lane>>4, c=lane&15;
  bf16x8 aq[2];
  {
    int qrow = q0 + 16*w + c;
    aq[0] = *(const bf16x8*)(qh + (size_t)qrow*HD + g*8);
    aq[1] = *(const bf16x8*)(qh + (size_t)qrow*HD + 32 + g*8);
  }
  f32x4 cacc[4] = {};
  float m_r[4], l_r[4];
  #pragma unroll
  for(int r=0;r<4;r++){ m_r[r] = -1e30f; l_r[r] = 0.f; }

  for(int kt=0; kt<16; kt++){
    int k0 = kt*64;
    __syncthreads();
    // stage rel1+rel2 (coalesced float4 — the HBM-critical reads)
    #pragma unroll
    for(int i=0;i<4;i++){
      int idx = i*256+t; int r = idx>>4; int cs = (idx&15)*4;
      f32x4 a = *(const f32x4*)(r1 + (size_t)(q0+r)*SS + k0 + cs);
      f32x4 b2= *(const f32x4*)(r2 + (size_t)(q0+r)*SS + k0 + cs);
      *(f32x4*)&relS[r][cs] = a + b2;
    }
    // stage K tile [s][d] swizzled
    #pragma unroll
    for(int i=0;i<2;i++){
      int id = i*256+t; int s = id>>3; int seg = id&7;
      bf16x8 kv = *(const bf16x8*)(kh + (size_t)(k0+s)*HD + seg*8);
      *(bf16x8*)&Ks[s*64 + ((seg ^ (s&7))<<3)] = kv;
    }
    // stage V transposed [d][s] swizzled
    #pragma unroll
    for(int i=0;i<2;i++){
      int id = i*256+t; int s = id&63; int seg = id>>6;   // seg 0..7 across 2 iters
      bf16x8 vv = *(const bf16x8*)(vh + (size_t)(k0+s)*HD + seg*8);
      #pragma unroll
      for(int j=0;j<8;j++){
        int d = seg*8+j;
        Vs[d*64 + (s ^ (j<<3))] = vv[j];
      }
    }
    __syncthreads();

    // QK^T -> 16x64 scores per wave
    f32x4 sc[4] = {};
    #pragma unroll
    for(int ks=0; ks<2; ks++){
      #pragma unroll
      for(int ct=0;ct<4;ct++){
        int scol = 16*ct + c;
        int seg = g + 4*ks;
        bf16x8 bk_ = *(const bf16x8*)&Ks[scol*64 + ((seg ^ (scol&7))<<3)];
        sc[ct] = mfma16(aq[ks], bk_, sc[ct]);
      }
    }
    // + rel biases
    #pragma unroll
    for(int ct=0;ct<4;ct++)
      #pragma unroll
      for(int r=0;r<4;r++)
        sc[ct][r] += relS[16*w + 4*g + r][16*ct + c];

    // online softmax (row = 16w+4g+r, cols spread over lane&15 groups)
    float rm[4];
    #pragma unroll
    for(int r=0;r<4;r++){
      float mv = fmaxf(fmaxf(sc[0][r],sc[1][r]), fmaxf(sc[2][r],sc[3][r]));
      #pragma unroll
      for(int mk=1; mk<16; mk<<=1) mv = fmaxf(mv, __shfl_xor(mv, mk));
      rm[r] = mv;
    }
    float pvv[4][4];
    #pragma unroll
    for(int r=0;r<4;r++){
      float mn = fmaxf(m_r[r], rm[r]);
      float corr = __expf(m_r[r] - mn);
      m_r[r] = mn;
      float ssum = 0.f;
      #pragma unroll
      for(int ct=0;ct<4;ct++){ float p = __expf(sc[ct][r]-mn); pvv[ct][r]=p; ssum += p; }
      #pragma unroll
      for(int mk=1; mk<16; mk<<=1) ssum += __shfl_xor(ssum, mk);
      l_r[r] = l_r[r]*corr + ssum;
      #pragma unroll
      for(int ct=0;ct<4;ct++) cacc[ct][r] *= corr;
    }
    // P -> per-wave LDS (transpose to A-fragment layout)
    #pragma unroll
    for(int ct=0;ct<4;ct++)
      #pragma unroll
      for(int r=0;r<4;r++){
        int row = 4*g + r, col = 16*ct + c;
        Ps[w][row*64 + (col ^ ((row&7)<<3))] = (bf16)pvv[ct][r];
      }
    // PV
    #pragma unroll
    for(int ks=0;ks<2;ks++){
      int seg = g + 4*ks;
      bf16x8 pa = *(const bf16x8*)&Ps[w][c*64 + ((seg ^ (c&7))<<3)];
      #pragma unroll
      for(int ct=0;ct<4;ct++){
        int d = 16*ct + c;
        bf16x8 bv_ = *(const bf16x8*)&Vs[d*64 + ((seg ^ (d&7))<<3)];
        cacc[ct] = mfma16(pa, bv_, cacc[ct]);
      }
    }
  }
  // ctx out (bf16, [token][H] with col = h*64+d)
  #pragma unroll
  for(int ct=0;ct<4;ct++)
    #pragma unroll
    for(int r=0;r<4;r++){
      int row = q0 + 16*w + 4*g + r;
      int col = 16*ct + c;
      float o = cacc[ct][r] / l_r[r];
      ctxb[((size_t)(b_*SS + row))*H + h*HD + col] = (bf16)o;
    }
}

// ---------------- output GEMM + bias + residual -> y (f32) ----------------
__global__ __launch_bounds__(256) void out_gemm(const bf16* __restrict__ ctxb, const bf16* __restrict__ woT,
    const float* __restrict__ bo, const float* __restrict__ hs, float* __restrict__ y){
  int t = threadIdx.x;
  int m0 = blockIdx.x*64, n0 = blockIdx.y*64;
  __shared__ __align__(16) bf16 As[64*40];
  __shared__ __align__(16) bf16 Bs[64*40];
  int lane=t&63, w=t>>6, g=lane>>4, c=lane&15;
  f32x4 acc[4] = {};
  int ar = t>>2, asg = (t&3)*8;
  for(int kt=0; kt<24; kt++){
    __syncthreads();
    *(bf16x8*)&As[ar*40+asg] = *(const bf16x8*)(ctxb + (size_t)(m0+ar)*H + kt*32 + asg);
    *(bf16x8*)&Bs[ar*40+asg] = *(const bf16x8*)(woT  + (size_t)(n0+ar)*H + kt*32 + asg);
    __syncthreads();
    bf16x8 a = *(const bf16x8*)&As[(16*w+c)*40 + g*8];
    #pragma unroll
    for(int ct=0;ct<4;ct++){
      bf16x8 b = *(const bf16x8*)&Bs[(16*ct+c)*40 + g*8];
      acc[ct] = mfma16(a, b, acc[ct]);
    }
  }
  #pragma unroll
  for(int ct=0;ct<4;ct++)
    #pragma unroll
    for(int r=0;r<4;r++){
      int row = m0 + 16*w + 4*g + r;
      int col = n0 + 16*ct + c;
      y[(size_t)row*H + col] = acc[ct][r] + bo[col] + hs[(size_t)row*H + col];
    }
}

// ---------------- LayerNorm (one row per block) ----------------
__global__ __launch_bounds__(256) void ln_kernel(const float* __restrict__ y,
    const float* __restrict__ gw, const float* __restrict__ bw, float* __restrict__ out){
  int row = blockIdx.x; int t = threadIdx.x;
  const float* yr = y + (size_t)row*H;
  float v0 = yr[t], v1 = yr[t+256], v2 = yr[t+512];
  float s = v0+v1+v2;
  #pragma unroll
  for(int mk=1; mk<64; mk<<=1) s += __shfl_xor(s, mk);
  __shared__ float red[8];
  int w = t>>6, lane = t&63;
  if(lane==0) red[w] = s;
  __syncthreads();
  float mu = (red[0]+red[1]+red[2]+red[3]) * (1.f/768.f);
  float d0=v0-mu, d1=v1-mu, d2=v2-mu;
  float s2 = d0*d0+d1*d1+d2*d2;
  #pragma unroll
  for(int mk=1; mk<64; mk<<=1) s2 += __shfl_xor(s2, mk);
  __syncthreads();
  if(lane==0) red[w] = s2;
  __syncthreads();
  float var = (red[0]+red[1]+red[2]+red[3]) * (1.f/768.f);
  float inv = rsqrtf(var + 1e-12f);
  out[(size_t)row*H + t]     = d0*inv*gw[t]     + bw[t];
  out[(size_t)row*H + t+256] = d1*inv*gw[t+256] + bw[t+256];
  out[(size_t)row*H + t+512] = d2*inv*gw[t+512] + bw[t+512];
}

extern "C" void kernel_launch(void* const* d_in, const int* in_sizes, int n_in,
                              void* d_out, int out_size, void* d_ws, size_t ws_size,
                              hipStream_t stream){
  const float* hs   = (const float*)d_in[0];
  const float* relp = (const float*)d_in[1];
  const float* rel2 = (const float*)d_in[2];
  const float* Wq   = (const float*)d_in[3];
  const float* bq   = (const float*)d_in[4];
  const float* Wk   = (const float*)d_in[5];
  const float* bk   = (const float*)d_in[6];
  const float* Wv   = (const float*)d_in[7];
  const float* bv   = (const float*)d_in[8];
  const float* Wo   = (const float*)d_in[9];
  const float* bo   = (const float*)d_in[10];
  const float* lng  = (const float*)d_in[11];
  const float* lnb  = (const float*)d_in[12];
  float* out = (float*)d_out;

  char* p = (char*)d_ws;
  bf16* hsb = (bf16*)p; p += (size_t)MM*H*2;
  bf16* wqT = (bf16*)p; p += (size_t)H*H*2;
  bf16* wkT = (bf16*)p; p += (size_t)H*H*2;
  bf16* wvT = (bf16*)p; p += (size_t)H*H*2;
  bf16* woT = (bf16*)p; p += (size_t)H*H*2;
  bf16* qbuf = (bf16*)p; p += (size_t)MM*H*2;
  bf16* kbuf = (bf16*)p; p += (size_t)MM*H*2;
  bf16* vbuf = (bf16*)p; p += (size_t)MM*H*2;
  bf16* ctxb = (bf16*)p; p += (size_t)MM*H*2;
  float* y   = (float*)p; p += (size_t)MM*H*4;

  prep_hs<<<dim3((MM*H/4)/256), 256, 0, stream>>>(hs, hsb);
  prep_wt<<<dim3(12,12,4), 256, 0, stream>>>(Wq, Wk, Wv, Wo, wqT, wkT, wvT, woT);
  qkv_gemm<<<dim3(64,36), 256, 0, stream>>>(hsb, wqT, wkT, wvT, bq, bk, bv, qbuf, kbuf, vbuf);
  attn_kernel<<<dim3(16,12,4), 256, 0, stream>>>(qbuf, kbuf, vbuf, relp, rel2, ctxb);
  out_gemm<<<dim3(64,12), 256, 0, stream>>>(ctxb, woT, bo, hs, y);
  ln_kernel<<<dim3(MM), 256, 0, stream>>>(y, lng, lnb, out);
}

// Round 2
// 180.727 us; speedup vs baseline: 1.1005x; 1.1005x over previous
//
#include <hip/hip_runtime.h>

#define H 768
#define NH 12
#define HD 64
#define BB 4
#define SS 1024
#define MM (BB*SS)   // 4096 tokens

typedef __bf16 bf16;
typedef __bf16 bf16x8 __attribute__((ext_vector_type(8)));
typedef __bf16 bf16x4 __attribute__((ext_vector_type(4)));
typedef float  f32x4  __attribute__((ext_vector_type(4)));

static __device__ __forceinline__ f32x4 mfma16(bf16x8 a, bf16x8 b, f32x4 c){
  return __builtin_amdgcn_mfma_f32_16x16x32_bf16(a, b, c, 0, 0, 0);
}

// ---------------- prep: hs -> bf16 ----------------
__global__ __launch_bounds__(256) void prep_hs(const float* __restrict__ hs, bf16* __restrict__ hsb){
  size_t i = (size_t)blockIdx.x*256 + threadIdx.x;   // one float4 each
  f32x4 v = *(const f32x4*)(hs + i*4);
  bf16x4 o;
  #pragma unroll
  for(int j=0;j<4;j++) o[j] = (bf16)v[j];
  *(bf16x4*)(hsb + i*4) = o;
}

// ---------------- prep: W[k][n] -> bf16 W^T[n][k] (LDS tiled transpose) ----------------
__global__ __launch_bounds__(256) void prep_wt(const float* __restrict__ Wq, const float* __restrict__ Wk,
                                               const float* __restrict__ Wv, const float* __restrict__ Wo,
                                               bf16* __restrict__ oq, bf16* __restrict__ ok,
                                               bf16* __restrict__ ov, bf16* __restrict__ oo){
  int z = blockIdx.z;
  const float* W = (z==0)?Wq:(z==1)?Wk:(z==2)?Wv:Wo;
  bf16* O = (z==0)?oq:(z==1)?ok:(z==2)?ov:oo;
  __shared__ float tile[64][65];
  int t = threadIdx.x;
  int k0 = blockIdx.y*64, n0 = blockIdx.x*64;
  #pragma unroll
  for(int i=0;i<4;i++){
    int idx = i*256+t; int r = idx>>4; int c4 = (idx&15)*4;
    f32x4 v = *(const f32x4*)(W + (size_t)(k0+r)*H + n0 + c4);
    tile[r][c4+0]=v[0]; tile[r][c4+1]=v[1]; tile[r][c4+2]=v[2]; tile[r][c4+3]=v[3];
  }
  __syncthreads();
  #pragma unroll
  for(int i=0;i<4;i++){
    int idx = i*256+t; int r = idx>>4; int c4 = (idx&15)*4;
    bf16x4 o;
    #pragma unroll
    for(int j=0;j<4;j++) o[j] = (bf16)tile[c4+j][r];
    *(bf16x4*)(O + (size_t)(n0+r)*H + k0 + c4) = o;
  }
}

// ---------------- QKV GEMM: [4096,768] x W^T -> q/k/v bf16 [B,NH,S,HD] ----------------
__global__ __launch_bounds__(256) void qkv_gemm(const bf16* __restrict__ hsb,
    const bf16* __restrict__ wqT, const bf16* __restrict__ wkT, const bf16* __restrict__ wvT,
    const float* __restrict__ bq, const float* __restrict__ bk, const float* __restrict__ bv,
    bf16* __restrict__ qb, bf16* __restrict__ kb, bf16* __restrict__ vb){
  int t = threadIdx.x;
  int m0 = blockIdx.x*64;
  int by = blockIdx.y;                 // 0..35
  int mat = by/12, nb = by%12, n0 = nb*64;
  const bf16* wT   = (mat==0)?wqT:(mat==1)?wkT:wvT;
  const float* bias= (mat==0)?bq :(mat==1)?bk :bv;
  bf16* outp       = (mat==0)?qb :(mat==1)?kb :vb;
  float scale      = (mat==0)?0.125f:1.0f;   // 1/sqrt(64) on q

  __shared__ __align__(16) bf16 As[64*40];   // 64 rows x 32 k, +8 pad
  __shared__ __align__(16) bf16 Bs[64*40];
  int lane=t&63, w=t>>6, g=lane>>4, c=lane&15;
  f32x4 acc[4] = {};
  int ar = t>>2, asg = (t&3)*8;
  for(int kt=0; kt<24; kt++){
    __syncthreads();
    *(bf16x8*)&As[ar*40+asg] = *(const bf16x8*)(hsb + (size_t)(m0+ar)*H + kt*32 + asg);
    *(bf16x8*)&Bs[ar*40+asg] = *(const bf16x8*)(wT  + (size_t)(n0+ar)*H + kt*32 + asg);
    __syncthreads();
    bf16x8 a = *(const bf16x8*)&As[(16*w+c)*40 + g*8];
    #pragma unroll
    for(int ct=0;ct<4;ct++){
      bf16x8 b = *(const bf16x8*)&Bs[(16*ct+c)*40 + g*8];
      acc[ct] = mfma16(a, b, acc[ct]);
    }
  }
  #pragma unroll
  for(int ct=0;ct<4;ct++){
    #pragma unroll
    for(int r=0;r<4;r++){
      int row = m0 + 16*w + 4*g + r;       // token index
      int col = 16*ct + c;                 // d within head (n0 spans exactly one head)
      float val = (acc[ct][r] + bias[n0+col]) * scale;
      int b_ = row>>10, s = row&1023;
      outp[(((size_t)(b_*NH + nb))*SS + s)*HD + col] = (bf16)val;
    }
  }
}

// ---------------- attention: one block per (b, h, 64 q-rows) ----------------
// T14 async-STAGE: rel1/rel2 loaded one tile ahead directly into D-fragment
// registers (no LDS round trip); K/V prefetched to regs, ds_written at top of
// next tile. Raw s_barrier (no vmcnt drain) keeps prefetch in flight.
__global__ __launch_bounds__(256,3) void attn_kernel(const bf16* __restrict__ qbuf,
    const bf16* __restrict__ kbuf, const bf16* __restrict__ vbuf,
    const float* __restrict__ relp, const float* __restrict__ rel2,
    bf16* __restrict__ ctxb){
  int t = threadIdx.x;
  int qt = blockIdx.x, h = blockIdx.y, b_ = blockIdx.z;
  int q0 = qt*64;
  const bf16* qh = qbuf + ((size_t)(b_*NH+h))*SS*HD;
  const bf16* kh = kbuf + ((size_t)(b_*NH+h))*SS*HD;
  const bf16* vh = vbuf + ((size_t)(b_*NH+h))*SS*HD;
  const float* r1 = relp + ((size_t)(b_*NH+h))*SS*SS;
  const float* r2 = rel2 + ((size_t)(b_*NH+h))*SS*SS;

  __shared__ __align__(16) bf16 Ks[64*64];   // [s][d] XOR-swizzled: s*64 + ((seg ^ (s&7))<<3)
  __shared__ __align__(16) bf16 Vs[64*64];   // [d][s] XOR-swizzled: d*64 + (s ^ ((d&7)<<3))
  __shared__ __align__(16) bf16 Ps[4][1024]; // per-wave P transpose

  int lane=t&63, w=t>>6, g=lane>>4, c=lane&15;

  // Q fragments (loaded once)
  bf16x8 aq[2];
  {
    int qrow = q0 + 16*w + c;
    aq[0] = *(const bf16x8*)(qh + (size_t)qrow*HD + g*8);
    aq[1] = *(const bf16x8*)(qh + (size_t)qrow*HD + 32 + g*8);
  }

  // rel fragment base pointers (row = q0+16w+4g+r, col = k0+16ct+c)
  const float* p1 = r1 + (size_t)(q0 + 16*w + 4*g)*SS + c;
  const float* p2 = r2 + (size_t)(q0 + 16*w + 4*g)*SS + c;

  // K staging coords: rows t>>3 and 32+(t>>3), seg t&7
  int ks_s = t>>3, ks_seg = t&7;
  int ks_lds = ks_s*64 + ((ks_seg ^ (ks_s&7))<<3);

  // prefetch registers (tile kt in flight / held)
  float rn1[16], rn2[16];
  bf16x8 kreg[2], vreg[2];

  // ---- prologue: issue loads for tile 0 ----
  kreg[0] = *(const bf16x8*)(kh + (size_t)ks_s*HD + ks_seg*8);
  kreg[1] = *(const bf16x8*)(kh + (size_t)(32+ks_s)*HD + ks_seg*8);
  vreg[0] = *(const bf16x8*)(vh + (size_t)lane*HD + w*8);
  vreg[1] = *(const bf16x8*)(vh + (size_t)lane*HD + (4+w)*8);
  #pragma unroll
  for(int ct=0;ct<4;ct++)
    #pragma unroll
    for(int r=0;r<4;r++){
      rn1[ct*4+r] = p1[(size_t)r*SS + 16*ct];
      rn2[ct*4+r] = p2[(size_t)r*SS + 16*ct];
    }

  f32x4 cacc[4] = {};
  float m_r[4], l_r[4];
  #pragma unroll
  for(int r=0;r<4;r++){ m_r[r] = -1e30f; l_r[r] = 0.f; }

  for(int kt=0; kt<16; kt++){
    int k0n = (kt<15) ? (kt+1)*64 : kt*64;   // clamped prefetch tile

    // (1) ds_write K/V of tile kt from regs (compiler inserts precise vmcnt wait)
    *(bf16x8*)&Ks[ks_lds]         = kreg[0];
    *(bf16x8*)&Ks[32*64 + ks_lds] = kreg[1];
    #pragma unroll
    for(int j=0;j<8;j++){
      Vs[(w*8+j)*64     + (lane ^ (j<<3))] = vreg[0][j];
      Vs[((4+w)*8+j)*64 + (lane ^ (j<<3))] = vreg[1][j];
    }
    // (2) issue K/V loads for tile kt+1
    kreg[0] = *(const bf16x8*)(kh + (size_t)(k0n+ks_s)*HD + ks_seg*8);
    kreg[1] = *(const bf16x8*)(kh + (size_t)(k0n+32+ks_s)*HD + ks_seg*8);
    vreg[0] = *(const bf16x8*)(vh + (size_t)(k0n+lane)*HD + w*8);
    vreg[1] = *(const bf16x8*)(vh + (size_t)(k0n+lane)*HD + (4+w)*8);

    // (3) LDS handoff barrier (raw: does NOT drain vmcnt)
    asm volatile("s_waitcnt lgkmcnt(0)" ::: "memory");
    __builtin_amdgcn_s_barrier();

    // (4) combine rel tile kt (waits only the rn loads; K/V prefetch stays in flight)
    float relC[16];
    #pragma unroll
    for(int i=0;i<16;i++) relC[i] = rn1[i] + rn2[i];
    // (5) issue rel loads for tile kt+1
    #pragma unroll
    for(int ct=0;ct<4;ct++)
      #pragma unroll
      for(int r=0;r<4;r++){
        rn1[ct*4+r] = p1[(size_t)r*SS + k0n + 16*ct];
        rn2[ct*4+r] = p2[(size_t)r*SS + k0n + 16*ct];
      }

    // (6) compute: QK^T -> 16x64 scores per wave
    f32x4 sc[4] = {};
    #pragma unroll
    for(int ks=0; ks<2; ks++){
      #pragma unroll
      for(int ct=0;ct<4;ct++){
        int scol = 16*ct + c;
        int seg = g + 4*ks;
        bf16x8 bk_ = *(const bf16x8*)&Ks[scol*64 + ((seg ^ (scol&7))<<3)];
        sc[ct] = mfma16(aq[ks], bk_, sc[ct]);
      }
    }
    #pragma unroll
    for(int ct=0;ct<4;ct++)
      #pragma unroll
      for(int r=0;r<4;r++)
        sc[ct][r] += relC[ct*4+r];

    // online softmax (row = 16w+4g+r, cols over c groups)
    #pragma unroll
    for(int r=0;r<4;r++){
      float mv = fmaxf(fmaxf(sc[0][r],sc[1][r]), fmaxf(sc[2][r],sc[3][r]));
      #pragma unroll
      for(int mk=1; mk<16; mk<<=1) mv = fmaxf(mv, __shfl_xor(mv, mk));
      float mn = fmaxf(m_r[r], mv);
      float corr = __expf(m_r[r] - mn);
      m_r[r] = mn;
      float ssum = 0.f;
      #pragma unroll
      for(int ct=0;ct<4;ct++){ float p = __expf(sc[ct][r]-mn); sc[ct][r]=p; ssum += p; }
      #pragma unroll
      for(int mk=1; mk<16; mk<<=1) ssum += __shfl_xor(ssum, mk);
      l_r[r] = l_r[r]*corr + ssum;
      #pragma unroll
      for(int ct=0;ct<4;ct++) cacc[ct][r] *= corr;
    }
    // P -> per-wave LDS (transpose to A-fragment layout)
    #pragma unroll
    for(int ct=0;ct<4;ct++)
      #pragma unroll
      for(int r=0;r<4;r++){
        int row = 4*g + r, col = 16*ct + c;
        Ps[w][row*64 + (col ^ ((row&7)<<3))] = (bf16)sc[ct][r];
      }
    // PV
    #pragma unroll
    for(int ks=0;ks<2;ks++){
      int seg = g + 4*ks;
      bf16x8 pa = *(const bf16x8*)&Ps[w][c*64 + ((seg ^ (c&7))<<3)];
      #pragma unroll
      for(int ct=0;ct<4;ct++){
        int d = 16*ct + c;
        bf16x8 bv_ = *(const bf16x8*)&Vs[d*64 + ((seg ^ (d&7))<<3)];
        cacc[ct] = mfma16(pa, bv_, cacc[ct]);
      }
    }
    // (7) protect Ks/Vs for next iteration's writes
    __builtin_amdgcn_s_barrier();
  }

  // ctx out (bf16, [token][H] with col = h*64+d)
  #pragma unroll
  for(int ct=0;ct<4;ct++)
    #pragma unroll
    for(int r=0;r<4;r++){
      int row = q0 + 16*w + 4*g + r;
      int col = 16*ct + c;
      float o = cacc[ct][r] / l_r[r];
      ctxb[((size_t)(b_*SS + row))*H + h*HD + col] = (bf16)o;
    }
}

// ---------------- output GEMM + bias + residual -> y (f32) ----------------
__global__ __launch_bounds__(256) void out_gemm(const bf16* __restrict__ ctxb, const bf16* __restrict__ woT,
    const float* __restrict__ bo, const float* __restrict__ hs, float* __restrict__ y){
  int t = threadIdx.x;
  int m0 = blockIdx.x*64, n0 = blockIdx.y*64;
  __shared__ __align__(16) bf16 As[64*40];
  __shared__ __align__(16) bf16 Bs[64*40];
  int lane=t&63, w=t>>6, g=lane>>4, c=lane&15;
  f32x4 acc[4] = {};
  int ar = t>>2, asg = (t&3)*8;
  for(int kt=0; kt<24; kt++){
    __syncthreads();
    *(bf16x8*)&As[ar*40+asg] = *(const bf16x8*)(ctxb + (size_t)(m0+ar)*H + kt*32 + asg);
    *(bf16x8*)&Bs[ar*40+asg] = *(const bf16x8*)(woT  + (size_t)(n0+ar)*H + kt*32 + asg);
    __syncthreads();
    bf16x8 a = *(const bf16x8*)&As[(16*w+c)*40 + g*8];
    #pragma unroll
    for(int ct=0;ct<4;ct++){
      bf16x8 b = *(const bf16x8*)&Bs[(16*ct+c)*40 + g*8];
      acc[ct] = mfma16(a, b, acc[ct]);
    }
  }
  #pragma unroll
  for(int ct=0;ct<4;ct++)
    #pragma unroll
    for(int r=0;r<4;r++){
      int row = m0 + 16*w + 4*g + r;
      int col = n0 + 16*ct + c;
      y[(size_t)row*H + col] = acc[ct][r] + bo[col] + hs[(size_t)row*H + col];
    }
}

// ---------------- LayerNorm (one row per block) ----------------
__global__ __launch_bounds__(256) void ln_kernel(const float* __restrict__ y,
    const float* __restrict__ gw, const float* __restrict__ bw, float* __restrict__ out){
  int row = blockIdx.x; int t = threadIdx.x;
  const float* yr = y + (size_t)row*H;
  float v0 = yr[t], v1 = yr[t+256], v2 = yr[t+512];
  float s = v0+v1+v2;
  #pragma unroll
  for(int mk=1; mk<64; mk<<=1) s += __shfl_xor(s, mk);
  __shared__ float red[8];
  int w = t>>6, lane = t&63;
  if(lane==0) red[w] = s;
  __syncthreads();
  float mu = (red[0]+red[1]+red[2]+red[3]) * (1.f/768.f);
  float d0=v0-mu, d1=v1-mu, d2=v2-mu;
  float s2 = d0*d0+d1*d1+d2*d2;
  #pragma unroll
  for(int mk=1; mk<64; mk<<=1) s2 += __shfl_xor(s2, mk);
  __syncthreads();
  if(lane==0) red[w] = s2;
  __syncthreads();
  float var = (red[0]+red[1]+red[2]+red[3]) * (1.f/768.f);
  float inv = rsqrtf(var + 1e-12f);
  out[(size_t)row*H + t]     = d0*inv*gw[t]     + bw[t];
  out[(size_t)row*H + t+256] = d1*inv*gw[t+256] + bw[t+256];
  out[(size_t)row*H + t+512] = d2*inv*gw[t+512] + bw[t+512];
}

extern "C" void kernel_launch(void* const* d_in, const int* in_sizes, int n_in,
                              void* d_out, int out_size, void* d_ws, size_t ws_size,
                              hipStream_t stream){
  const float* hs   = (const float*)d_in[0];
  const float* relp = (const float*)d_in[1];
  const float* rel2 = (const float*)d_in[2];
  const float* Wq   = (const float*)d_in[3];
  const float* bq   = (const float*)d_in[4];
  const float* Wk   = (const float*)d_in[5];
  const float* bk   = (const float*)d_in[6];
  const float* Wv   = (const float*)d_in[7];
  const float* bv   = (const float*)d_in[8];
  const float* Wo   = (const float*)d_in[9];
  const float* bo   = (const float*)d_in[10];
  const float* lng  = (const float*)d_in[11];
  const float* lnb  = (const float*)d_in[12];
  float* out = (float*)d_out;

  char* p = (char*)d_ws;
  bf16* hsb = (bf16*)p; p += (size_t)MM*H*2;
  bf16* wqT = (bf16*)p; p += (size_t)H*H*2;
  bf16* wkT = (bf16*)p; p += (size_t)H*H*2;
  bf16* wvT = (bf16*)p; p += (size_t)H*H*2;
  bf16* woT = (bf16*)p; p += (size_t)H*H*2;
  bf16* qbuf = (bf16*)p; p += (size_t)MM*H*2;
  bf16* kbuf = (bf16*)p; p += (size_t)MM*H*2;
  bf16* vbuf = (bf16*)p; p += (size_t)MM*H*2;
  bf16* ctxb = (bf16*)p; p += (size_t)MM*H*2;
  float* y   = (float*)p; p += (size_t)MM*H*4;

  prep_hs<<<dim3((MM*H/4)/256), 256, 0, stream>>>(hs, hsb);
  prep_wt<<<dim3(12,12,4), 256, 0, stream>>>(Wq, Wk, Wv, Wo, wqT, wkT, wvT, woT);
  qkv_gemm<<<dim3(64,36), 256, 0, stream>>>(hsb, wqT, wkT, wvT, bq, bk, bv, qbuf, kbuf, vbuf);
  attn_kernel<<<dim3(16,12,4), 256, 0, stream>>>(qbuf, kbuf, vbuf, relp, rel2, ctxb);
  out_gemm<<<dim3(64,12), 256, 0, stream>>>(ctxb, woT, bo, hs, y);
  ln_kernel<<<dim3(MM), 256, 0, stream>>>(y, lng, lnb, out);
}